// Round 11
// baseline (215.262 us; speedup 1.0000x reference)
//
#include <hip/hip_runtime.h>
#include <stdint.h>

// Problem constants (fixed by the reference setup)
#define B_ 32
#define I_ 16384
#define H_ 1024
#define T_ 10
#define M_ 320   // T_*B_  (GEMM M dimension, m = t*32 + b)
#define NW 64    // GEMM per-block n-tile width
#define BK 32    // K rows per pipeline stage
#define KS_ 32   // K-split (round 11: revert to 32 -- r6 vs r10 A/B: 61.6 vs 63.4)
#define SCAN_BLOCKS 256   // H_/4

typedef __attribute__((ext_vector_type(8))) short short8;  // 8 bf16 (4 VGPRs)
typedef __attribute__((ext_vector_type(4))) float f32x4;
typedef __attribute__((ext_vector_type(2))) float f32x2;
typedef __attribute__((ext_vector_type(4))) unsigned int u32x4;

// ---------------------------------------------------------------------------
// Kernel 1: pack spikes [B][I][T] f32 -> Sbf [M=T*B][I] bf16 (exact: 0/1)
// ROUND-11: 64 i-columns per block (was 32) -> global writes become 128-B
// contiguous segments (min DRAM burst) instead of 64-B; write segment count
// halves.  LDS row pad = 68 ushorts: read-phase banks (m*34+il8*4)%32 are
// <=2-way across a wave (free).  Value mapping unchanged.
// ---------------------------------------------------------------------------
__global__ __launch_bounds__(256) void pack_s(const float* __restrict__ spikes,
                                              uint16_t* __restrict__ Sbf) {
  __shared__ __align__(16) uint16_t tile[M_ * 68];  // [m][il], il<64 pad->68
  const int i0 = blockIdx.x * 64;
#pragma unroll
  for (int p = 0; p < 20; p++) {
    int e = p * 256 + threadIdx.x;          // f32x4 index
    int b = e / 160;                         // 160 f32x4 per b-row (64 cols x 10 t)
    int r = e - b * 160;
    f32x4 val = *(const f32x4*)&spikes[(size_t)b * (I_ * T_) + (size_t)i0 * T_ + r * 4];
#pragma unroll
    for (int j = 0; j < 4; j++) {
      int pos = r * 4 + j;                   // pos = il*10 + t  (il 0..63)
      int il = pos / 10;
      int t = pos - il * 10;
      float f = (j == 0) ? val.x : (j == 1) ? val.y : (j == 2) ? val.z : val.w;
      union { float f; unsigned int u; } cv; cv.f = f;
      tile[(t * 32 + b) * 68 + il] = (uint16_t)(cv.u >> 16);  // exact for 0/1
    }
  }
  __syncthreads();
#pragma unroll
  for (int p = 0; p < 10; p++) {
    int e = p * 256 + threadIdx.x;
    int m = e >> 3, il8 = e & 7;             // 8 u32x4 chunks per 64-col row
    u32x4 w = *(const u32x4*)&tile[m * 68 + il8 * 8];
    *(u32x4*)&Sbf[(size_t)m * I_ + i0 + il8 * 8] = w;
  }
}

// ---------------------------------------------------------------------------
// Kernel 2: GEMM  partial[ks][320][1024] = Sbf * (weight*strength)
// 2-term bf16 split (w = hi + lo); fp32-class accuracy.
// ROUND-11: exact round-6 pipeline and KS=32 (best measured: 60.4-61.8 us).
// r10 A/B proved partial writes are free (WRITE halved, time unchanged);
// the ~2 TB/s W/S read-pattern service rate is the established ceiling
// (depth r9, blocks/CU r6, segment width r4, writes r10 all exonerated).
// Pipeline: reg-staged W/S, raw s_barrier + lgkmcnt-only (loads live
// across barriers), 1-stage lead.  MFMA k-order: ascending 32-k subtiles,
// hi then lo (identical to all prior rounds -> bit-identical output).
// ---------------------------------------------------------------------------
__global__ __launch_bounds__(640, 5) void gemm(const uint16_t* __restrict__ Sbf,
                                               const float* __restrict__ Wg,
                                               const float* __restrict__ Sg,
                                               float* __restrict__ partial,
                                               int kchunk, int KS) {
  __shared__ __align__(16) uint16_t WhiL[2][NW * 40];  // 5.12 KB each buf
  __shared__ __align__(16) uint16_t WloL[2][NW * 40];

  const int ks = blockIdx.x % KS;      // ks fastest: same-ks blocks same XCD
  const int nt = blockIdx.x / KS;
  const int nbase = nt * NW;
  const int tid = threadIdx.x;
  const int lane = tid & 63, wid = tid >> 6;   // wid 0..9
  const int quad = lane >> 4, l15 = lane & 15;

  const int stages = kchunk >> 5;      // BK = 32
  const int kofs = ks * kchunk;

  // A-fragment pointers: lane holds A[m][quad*8 + j] -> 16B contiguous global
  const uint16_t* aptr0 = Sbf + (size_t)(wid * 32 + l15) * I_ + quad * 8;
  const uint16_t* aptr1 = aptr0 + (size_t)16 * I_;

  // W staging mapping (tid < 256): n-column x k-octet (4 octets = 32 k)
  const int wn = tid & 63;             // adjacent lanes -> adjacent columns
  const int wko = (tid >> 6) & 3;      // k-octet within the 32-k stage

  f32x4 acc[2][4];
#pragma unroll
  for (int a = 0; a < 2; a++)
#pragma unroll
    for (int b = 0; b < 4; b++) acc[a][b] = f32x4{0.f, 0.f, 0.f, 0.f};

  u32x4 af[2];                         // current-stage A fragments
  float wpre[8], spre[8];

  // Raw barrier: LDS-write visibility only; vmem loads stay in flight.
#define BAR()                                                               \
  do {                                                                      \
    asm volatile("s_waitcnt lgkmcnt(0)" ::: "memory");                      \
    __builtin_amdgcn_s_barrier();                                           \
    __builtin_amdgcn_sched_barrier(0);                                      \
  } while (0)

  // pack wpre/spre -> hi/lo planes of LDS buffer pn
#define PACK_W(pn)                                                          \
  if (tid < 256) {                                                          \
    unsigned int hw[4], lw[4];                                              \
    _Pragma("unroll")                                                       \
    for (int j2 = 0; j2 < 4; j2++) {                                        \
      unsigned int hh[2], ll[2];                                            \
      _Pragma("unroll")                                                     \
      for (int e = 0; e < 2; e++) {                                         \
        float p = wpre[j2 * 2 + e] * spre[j2 * 2 + e];                      \
        union { float f; unsigned int u; } cv; cv.f = p;                    \
        unsigned int hb = (cv.u + 0x7FFFu + ((cv.u >> 16) & 1u)) >> 16;     \
        union { unsigned int u; float f; } hv; hv.u = hb << 16;             \
        float lo = p - hv.f;                                                \
        union { float f; unsigned int u; } cl; cl.f = lo;                   \
        unsigned int lb = (cl.u + 0x7FFFu + ((cl.u >> 16) & 1u)) >> 16;     \
        hh[e] = hb; ll[e] = lb;                                             \
      }                                                                     \
      hw[j2] = hh[0] | (hh[1] << 16);                                       \
      lw[j2] = ll[0] | (ll[1] << 16);                                       \
    }                                                                       \
    int wofs = wn * 40 + wko * 8;                                           \
    *(u32x4*)&WhiL[pn][wofs] = u32x4{hw[0], hw[1], hw[2], hw[3]};           \
    *(u32x4*)&WloL[pn][wofs] = u32x4{lw[0], lw[1], lw[2], lw[3]};           \
  }

#define LOAD_W(kb)                                                          \
  if (tid < 256) {                                                          \
    _Pragma("unroll")                                                       \
    for (int j = 0; j < 8; j++) {                                           \
      size_t g = (size_t)((kb) + wko * 8 + j) * H_ + nbase + wn;            \
      wpre[j] = Wg[g]; spre[j] = Sg[g];                                     \
    }                                                                       \
  }

#define ISSUE_A(kb)                                                         \
  {                                                                         \
    af[0] = *(const u32x4*)(aptr0 + (kb));                                  \
    af[1] = *(const u32x4*)(aptr1 + (kb));                                  \
  }

#define COMPUTE(pc)                                                         \
  {                                                                         \
    short8 a0 = __builtin_bit_cast(short8, af[0]);                          \
    short8 a1 = __builtin_bit_cast(short8, af[1]);                          \
    _Pragma("unroll")                                                       \
    for (int tn = 0; tn < 4; ++tn) {                                        \
      int n = tn * 16 + l15;                                                \
      short8 bhi = *(const short8*)&WhiL[pc][n * 40 + quad * 8];            \
      short8 blo = *(const short8*)&WloL[pc][n * 40 + quad * 8];            \
      acc[0][tn] = __builtin_amdgcn_mfma_f32_16x16x32_bf16(a0, bhi, acc[0][tn], 0, 0, 0); \
      acc[0][tn] = __builtin_amdgcn_mfma_f32_16x16x32_bf16(a0, blo, acc[0][tn], 0, 0, 0); \
      acc[1][tn] = __builtin_amdgcn_mfma_f32_16x16x32_bf16(a1, bhi, acc[1][tn], 0, 0, 0); \
      acc[1][tn] = __builtin_amdgcn_mfma_f32_16x16x32_bf16(a1, blo, acc[1][tn], 0, 0, 0); \
    }                                                                       \
  }

  // ---- prologue: stage 0 packed, stage 1 loads in flight ----
  LOAD_W(kofs);
  ISSUE_A(kofs);
  PACK_W(0);                           // waits stage-0 W regs, fills buf0
  if (stages > 1) LOAD_W(kofs + BK);   // stage 1: issue only
  BAR();

  // ---- main loop: loads for s+1 are in flight while computing s ----
  for (int s = 0; s < stages; ++s) {
    COMPUTE(s & 1);
    if (s + 1 < stages) {
      ISSUE_A(kofs + (s + 1) * BK);
      PACK_W((s + 1) & 1);             // waits W(s+1) regs; writes other buf
      if (s + 2 < stages) LOAD_W(kofs + (s + 2) * BK);
      BAR();
    }
  }

  // ---- epilogue: C/D layout col=lane&15, row=quad*4+reg ----
#pragma unroll
  for (int tm = 0; tm < 2; tm++)
#pragma unroll
    for (int tn = 0; tn < 4; tn++) {
      int mrow = wid * 32 + tm * 16 + quad * 4;
      int ncol = nbase + tn * 16 + l15;
      float* dst = partial + ((size_t)ks * M_ + mrow) * H_ + ncol;
      dst[0 * H_] = acc[tm][tn].x;
      dst[1 * H_] = acc[tm][tn].y;
      dst[2 * H_] = acc[tm][tn].z;
      dst[3 * H_] = acc[tm][tn].w;
    }
#undef PACK_W
#undef LOAD_W
#undef ISSUE_A
#undef COMPUTE
#undef BAR
}

// ---------------------------------------------------------------------------
// Kernel 3: deterministic reduction of K-split partials -> weighted [320][1024]
// Compile-time unroll for KS=32/16; single accumulator, ascending k order.
// ---------------------------------------------------------------------------
__global__ __launch_bounds__(256) void reduce_w(const float* __restrict__ partial,
                                                float* __restrict__ weighted,
                                                int KS) {
  int j = (blockIdx.x * 256 + threadIdx.x) * 4;
  f32x4 s = f32x4{0.f, 0.f, 0.f, 0.f};
  if (KS == 32) {
#pragma unroll
    for (int k = 0; k < 32; k++) {
      f32x4 p = *(const f32x4*)&partial[(size_t)k * (M_ * H_) + j];
      s += p;
    }
  } else if (KS == 16) {
#pragma unroll
    for (int k = 0; k < 16; k++) {
      f32x4 p = *(const f32x4*)&partial[(size_t)k * (M_ * H_) + j];
      s += p;
    }
  } else {
    for (int k = 0; k < KS; k++) {
      f32x4 p = *(const f32x4*)&partial[(size_t)k * (M_ * H_) + j];
      s += p;
    }
  }
  *(f32x4*)&weighted[j] = s;
}

// ---------------------------------------------------------------------------
// Kernel 4: LIF scan (round-5 structure).  One thread per (b,h); win[t]
// preloaded to regs; zero atomics; diag via shfl trees + per-block partials.
// ---------------------------------------------------------------------------
__global__ __launch_bounds__(128) void scan(const float* __restrict__ weighted,
                                            const float* __restrict__ threshold,
                                            const float* __restrict__ fre0,
                                            const float* __restrict__ p_tau_mem,
                                            const float* __restrict__ p_tau_syn,
                                            const float* __restrict__ p_target,
                                            const float* __restrict__ p_lr,
                                            float* __restrict__ out,
                                            float* __restrict__ dpart) {
  const int tid = threadIdx.x;
  const int lane = tid & 63;
  const int wv = tid >> 6;             // wave 0..1
  const int b = lane & 31;             // batch (shfl-reduce dimension)
  const int hg = lane >> 5;            // h within wave (0..1)
  const int h = blockIdx.x * 4 + wv * 2 + hg;

  const float alpha_mem = expf(-0.001f / p_tau_mem[0]);
  const float alpha_syn = expf(-0.001f / p_tau_syn[0]);
  const float target = p_target[0], lr = p_lr[0];

  float win[T_];
#pragma unroll
  for (int t = 0; t < T_; t++)
    win[t] = weighted[(size_t)(t * 32 + b) * H_ + h];

  float fre = fre0[h];
  float thr = threshold[h];
  float v = 0.f, isyn = 0.f;
  float spk[T_], dv[T_], dr[T_], dtt[T_];

#pragma unroll
  for (int t = 0; t < T_; t++) {
    isyn = alpha_syn * isyn + win[t];
    v = alpha_mem * v + isyn;
    float spike = (v >= thr) ? 1.f : 0.f;
    v -= spike * thr;
    spk[t] = spike;
    // spike count over the 32 b-lanes of this h (exact integer sum)
    float r = spike;
    r += __shfl_xor(r, 1);
    r += __shfl_xor(r, 2);
    r += __shfl_xor(r, 4);
    r += __shfl_xor(r, 8);
    r += __shfl_xor(r, 16);
    float rate = r * (1.f / 32.f);
    fre = 0.99f * fre + 0.01f * rate;            // identical in 32 lanes
    thr = thr + lr * (fre - target);
    // diagnostics (wave partials, deterministic trees)
    float vv = v;
#pragma unroll
    for (int off = 1; off <= 32; off <<= 1) vv += __shfl_xor(vv, off);
    float r2 = r + __shfl_xor(r, 32);            // counts: h0+h1 (uniform)
    float t2 = thr + __shfl_xor(thr, 32);        // thr: h0+h1 (uniform)
    dv[t] = vv;                                  // sum v over 64 lanes
    dr[t] = r2 * (1.f / 32.f);                   // rate_h0 + rate_h1 (exact)
    dtt[t] = t2;
  }

  // spike output: 10 contiguous floats at out[b*H*T + h*T]
  {
    float* o = out + (size_t)b * (H_ * T_) + (size_t)h * T_;
#pragma unroll
    for (int p = 0; p < 5; p++)
      *(f32x2*)&o[p * 2] = f32x2{spk[p * 2], spk[p * 2 + 1]};
  }

  // block diag partial: combine the 2 waves via LDS, write 30 floats
  __shared__ float dl[2][30];
  if (lane == 0) {
#pragma unroll
    for (int t = 0; t < T_; t++) {
      dl[wv][t] = dv[t];
      dl[wv][10 + t] = dr[t];
      dl[wv][20 + t] = dtt[t];
    }
  }
  __syncthreads();
  if (tid < 30) dpart[(size_t)blockIdx.x * 30 + tid] = dl[0][tid] + dl[1][tid];
}

// ---------------------------------------------------------------------------
// Kernel 5: reduce the 256x30 diag partials -> out[327680..327709].
// ROUND-11: parallelized -- 960 threads = 30 counters x 32 groups; each
// thread sums 8 strided k (parallel loads), LDS-combine 32 groups/counter.
// (old version: 64-deep SERIAL load chain in 1 block ~ 8 us -> ~2 us.)
// ---------------------------------------------------------------------------
__global__ __launch_bounds__(960) void reduce_d(const float* __restrict__ dpart,
                                                float* __restrict__ out) {
  __shared__ float accl[30][33];
  const int c = threadIdx.x >> 5;      // counter 0..29
  const int g = threadIdx.x & 31;      // group 0..31
  float sum = 0.f;
#pragma unroll
  for (int j = 0; j < 8; j++) {
    int k = g + 32 * j;
    sum += dpart[(size_t)k * 30 + c];
  }
  accl[c][g] = sum;
  __syncthreads();
  if (threadIdx.x < 30) {
    float tot = 0.f;
#pragma unroll
    for (int g2 = 0; g2 < 32; g2++) tot += accl[threadIdx.x][g2];
    float scale = (threadIdx.x < 10) ? (1.f / 32768.f) : (1.f / 1024.f);
    out[327680 + threadIdx.x] = tot * scale;
  }
}

// ---------------------------------------------------------------------------
extern "C" void kernel_launch(void* const* d_in, const int* in_sizes, int n_in,
                              void* d_out, int out_size, void* d_ws, size_t ws_size,
                              hipStream_t stream) {
  const float* spikes    = (const float*)d_in[0];
  const float* weight    = (const float*)d_in[1];
  const float* strength  = (const float*)d_in[2];
  const float* threshold = (const float*)d_in[3];
  const float* fre0      = (const float*)d_in[4];
  const float* tau_mem   = (const float*)d_in[5];
  const float* tau_syn   = (const float*)d_in[6];
  const float* target    = (const float*)d_in[7];
  const float* lr        = (const float*)d_in[8];
  float* out = (float*)d_out;

  const size_t sbf_bytes = (size_t)M_ * I_ * 2;   // 10.5 MB bf16 A-matrix
  const size_t slice     = (size_t)M_ * H_ * 4;   // 1.31 MB per K-split partial
  const size_t wt_bytes  = (size_t)M_ * H_ * 4;   // weighted
  const size_t dp_bytes  = (size_t)SCAN_BLOCKS * 30 * 4;
  int KS = KS_;                                   // shrink if ws is small
  while (KS > 1 &&
         sbf_bytes + (size_t)KS * slice + wt_bytes + dp_bytes > ws_size)
    KS >>= 1;

  uint16_t* Sbf   = (uint16_t*)d_ws;
  float* partial  = (float*)((char*)d_ws + sbf_bytes);
  float* weighted = (float*)((char*)d_ws + sbf_bytes + (size_t)KS * slice);
  float* dpart    = (float*)((char*)d_ws + sbf_bytes + (size_t)KS * slice + wt_bytes);

  pack_s<<<I_ / 64, 256, 0, stream>>>(spikes, Sbf);
  gemm<<<(H_ / NW) * KS, 640, 0, stream>>>(Sbf, weight, strength, partial,
                                           I_ / KS, KS);
  reduce_w<<<(M_ * H_) / 1024, 256, 0, stream>>>(partial, weighted, KS);
  scan<<<SCAN_BLOCKS, 128, 0, stream>>>(weighted, threshold, fre0, tau_mem,
                                        tau_syn, target, lr, out, dpart);
  reduce_d<<<1, 960, 0, stream>>>(dpart, out);
}